// Round 3
// baseline (316.351 us; speedup 1.0000x reference)
//
#include <hip/hip_runtime.h>
#include <hip/hip_fp16.h>
#include <math.h>

#define D 64
#define RB_SHIFT 6          // 64 rows per bucket
#define RB 64
#define CAPE 2048           // padded edges per bucket (expected ~1150, +30 sigma safe)
#define LDSE 2048           // LDS desc stage: worst case = whole bucket (16 KB)

// ---------------- direct CSR build (no binned intermediate) ----------------

// Pass 1: global row histogram. 1.25M atomics over 100K addresses -> ~12
// collisions/address, no hot spot.
__global__ void hist_kernel(const int* __restrict__ row, int* __restrict__ rowcnt, int E) {
    int tid = blockIdx.x * blockDim.x + threadIdx.x;
    int stride = gridDim.x * blockDim.x;
    int n4 = E >> 2;
    const int4* r4 = (const int4*)row;
    for (int i = tid; i < n4; i += stride) {
        int4 r = r4[i];
        atomicAdd(&rowcnt[r.x], 1);
        atomicAdd(&rowcnt[r.y], 1);
        atomicAdd(&rowcnt[r.z], 1);
        atomicAdd(&rowcnt[r.w], 1);
    }
    for (int i = (n4 << 2) + tid; i < E; i += stride)
        atomicAdd(&rowcnt[row[i]], 1);
}

// Pass 2: one 64-thread block per 64-row bucket. Rows padded to a multiple of
// 4 AND to the max of their row-QUAD (rows 4m..4m+3) so the SpMM runs one row
// per 16-lane group with a wave-uniform loop bound. Emits rowinfo
// (start, padded_quad_len), inits the per-row scatter cursor, and writes the
// pad descriptors (col-offset 0 = node 0, w = 0) directly to edges.
__global__ void scan_pad_kernel(const int* __restrict__ rowcnt,
                                int2* __restrict__ edges,
                                int2* __restrict__ rowinfo,
                                int* __restrict__ curs, int N) {
    __shared__ int plr[RB];
    __shared__ int scn[RB];
    int b = blockIdx.x, t = threadIdx.x;            // t in [0, 64)
    int r = b * RB + t;
    int h = (r < N) ? rowcnt[r] : 0;
    plr[t] = (h + 3) & ~3;                          // row padded length (mult of 4)
    __syncthreads();
    int qb = t & ~3;                                // quad-common padded length
    int pl = max(max(plr[qb], plr[qb | 1]), max(plr[qb | 2], plr[qb | 3]));
    scn[t] = pl;
    __syncthreads();
    for (int off = 1; off < RB; off <<= 1) {        // inclusive scan
        int v = (t >= off) ? scn[t - off] : 0;
        __syncthreads();
        scn[t] += v;
        __syncthreads();
    }
    int ps = scn[t] - pl;                           // padded exclusive start (mult of 4)
    if (ps + pl > CAPE) { ps = 0; pl = 0; h = 0; }  // pathological-skew guard (+30 sigma)
    if (r < N) {
        int start = b * CAPE + ps;
        rowinfo[r] = make_int2(start, pl);
        curs[r] = start;
        for (int i = h; i < pl; ++i) edges[start + i] = make_int2(0, 0);  // pad: w = 0
    }
}

// Pass 3: scatter each edge directly to its final slot. Desc: x = col<<7
// (byte offset of z row), y = w as duplicated-half2 bits. Within-row order is
// atomic-arbitrary (was already arbitrary before; sum order-independent to
// the test tolerance).
__global__ void scatter_kernel(const int* __restrict__ row, const int* __restrict__ col,
                               const float* __restrict__ w,
                               int* __restrict__ curs, int2* __restrict__ edges, int E) {
    int tid = blockIdx.x * blockDim.x + threadIdx.x;
    int stride = gridDim.x * blockDim.x;
    int n4 = E >> 2;
    const int4* r4 = (const int4*)row;
    const int4* c4 = (const int4*)col;
    const float4* w4 = (const float4*)w;
    for (int i = tid; i < n4; i += stride) {
        int4 rr = r4[i];
        int4 cc = c4[i];
        float4 ww = w4[i];
        int rs[4] = {rr.x, rr.y, rr.z, rr.w};
        int cs[4] = {cc.x, cc.y, cc.z, cc.w};
        float wf[4] = {ww.x, ww.y, ww.z, ww.w};
#pragma unroll
        for (int q = 0; q < 4; ++q) {
            int pos = atomicAdd(&curs[rs[q]], 1);
            __half2 wh2 = __half2half2(__float2half(wf[q]));
            edges[pos] = make_int2(cs[q] << 7, *(int*)&wh2);
        }
    }
    for (int i = (n4 << 2) + tid; i < E; i += stride) {
        int pos = atomicAdd(&curs[row[i]], 1);
        __half2 wh2 = __half2half2(__float2half(w[i]));
        edges[pos] = make_int2(col[i] << 7, *(int*)&wh2);
    }
}

// fp32 -> fp16 convert (vectorized)
__global__ void tohalf_kernel(const float4* __restrict__ in, ushort4* __restrict__ o, int n4) {
    int i = blockIdx.x * blockDim.x + threadIdx.x;
    int stride = gridDim.x * blockDim.x;
    for (; i < n4; i += stride) {
        float4 f = in[i];
        ushort4 h;
        h.x = __half_as_ushort(__float2half(f.x));
        h.y = __half_as_ushort(__float2half(f.y));
        h.z = __half_as_ushort(__float2half(f.z));
        h.w = __half_as_ushort(__float2half(f.w));
        o[i] = h;
    }
}

// ---- per-16-lane-group row gather-accumulate, descriptors from LDS ----
// Wave = 4 rows (one per 16-lane group); lane k16 owns features [4k16, 4k16+4)
// = 8 bytes of the z row. Per chunk of 4 edges: 2x ds_read_b128 (4 descs,
// broadcast within group) + 4x dwordx2 gather (64 lanes x 8 B = 512 B = 4
// fully-used cache lines) + 8x hfma2.
__device__ __forceinline__ void quad_row_acc_lds(const int2* __restrict__ lds_desc, int cnt,
                                                 const char* __restrict__ g2b, int boff,
                                                 __half2& acc0, __half2& acc1) {
    acc0 = __half2half2(__ushort_as_half((unsigned short)0));
    acc1 = acc0;
    for (int jb = 0; jb < cnt; jb += 4) {
        const int4* p4 = (const int4*)(lds_desc + jb);
        int4 d0 = p4[0];
        int4 d1 = p4[1];
        int2 g0 = *(const int2*)(g2b + (size_t)(unsigned)(d0.x + boff));
        int2 g1 = *(const int2*)(g2b + (size_t)(unsigned)(d0.z + boff));
        int2 g2 = *(const int2*)(g2b + (size_t)(unsigned)(d1.x + boff));
        int2 g3 = *(const int2*)(g2b + (size_t)(unsigned)(d1.z + boff));
        acc0 = __hfma2(*(__half2*)&d0.y, *(__half2*)&g0.x, acc0);
        acc1 = __hfma2(*(__half2*)&d0.y, *(__half2*)&g0.y, acc1);
        acc0 = __hfma2(*(__half2*)&d0.w, *(__half2*)&g1.x, acc0);
        acc1 = __hfma2(*(__half2*)&d0.w, *(__half2*)&g1.y, acc1);
        acc0 = __hfma2(*(__half2*)&d1.y, *(__half2*)&g2.x, acc0);
        acc1 = __hfma2(*(__half2*)&d1.y, *(__half2*)&g2.y, acc1);
        acc0 = __hfma2(*(__half2*)&d1.w, *(__half2*)&g3.x, acc0);
        acc1 = __hfma2(*(__half2*)&d1.w, *(__half2*)&g3.y, acc1);
    }
}

// ---------------- SpMM z-producer: z = cA * (A gsrc) + cC * zp2 ----------------
// One block = 4 waves = 16 consecutive rows (inside one 64-row bucket, so
// their descs are one contiguous span in edges). Stage span -> LDS, then one
// wave = 4 rows (one per 16-lane group).
__global__ void spmm_z_kernel(const int2* __restrict__ rowinfo,
                              const int2* __restrict__ edges,
                              const __half2* __restrict__ gsrc2,
                              const __half2* __restrict__ zp2_2,   // may be null
                              __half2* __restrict__ zdst2,
                              float cA, float cC, int N) {
    __shared__ alignas(16) int2 lds[LDSE];   // 16 KB
    int t = threadIdx.x;
    int bid = blockIdx.x;
    int r0 = bid * 16;

    // block-uniform desc span (contiguous by construction)
    int gs = rowinfo[r0].x;
    int2 rlast = rowinfo[min(r0 + 15, N - 1)];
    int span = rlast.x + rlast.y - gs;
    if (span > LDSE) span = LDSE;                      // pathological-skew guard
    {   // span and gs are multiples of 4 descs -> int4 staging
        int n4 = span >> 1;
        const int4* s4 = (const int4*)(edges + gs);
        int4* d4 = (int4*)lds;
        for (int i = t; i < n4; i += 256) d4[i] = s4[i];
    }
    __syncthreads();

    int wv = t >> 6;
    int lane = t & 63;
    int q = lane >> 4;
    int k16 = lane & 15;
    int rr = r0 + wv * 4 + q;
    bool valid = rr < N;
    int r = valid ? rr : N - 1;

    int2 ri = rowinfo[r];
    int cnt = __builtin_amdgcn_readfirstlane(ri.y);   // quad-common length
    int off = ri.x - gs;
    if (off < 0 || off + cnt > span) off = 0;         // safety

    int boff = k16 * 8;                                // byte offset within z row
    size_t rb = (size_t)r * 128 + boff;
    // issue epilogue input early so its latency hides under the acc loop
    float2 p0 = make_float2(0.f, 0.f), p1 = p0;
    if (zp2_2) {
        int2 pz = *(const int2*)((const char*)zp2_2 + rb);
        p0 = __half22float2(*(__half2*)&pz.x);
        p1 = __half22float2(*(__half2*)&pz.y);
    }

    __half2 acc0, acc1;
    quad_row_acc_lds(lds + off, cnt, (const char*)gsrc2, boff, acc0, acc1);
    float2 a0 = __half22float2(acc0);
    float2 a1 = __half22float2(acc1);

    float2 z0 = make_float2(cA * a0.x, cA * a0.y);
    float2 z1 = make_float2(cA * a1.x, cA * a1.y);
    if (zp2_2) {
        z0.x = fmaf(cC, p0.x, z0.x); z0.y = fmaf(cC, p0.y, z0.y);
        z1.x = fmaf(cC, p1.x, z1.x); z1.y = fmaf(cC, p1.y, z1.y);
    }
    if (valid) {
        __half2 h0 = __floats2half2_rn(z0.x, z0.y);
        __half2 h1 = __floats2half2_rn(z1.x, z1.y);
        int2 st;
        st.x = *(int*)&h0;
        st.y = *(int*)&h1;
        *(int2*)((char*)zdst2 + rb) = st;
    }
}

// ---------------- final SpMM + full output reduction ----------------
// z3 = cA*(A z2h) + cC*z1h (in-register);
// out = 0.25*(t0*xh + t1*z1h + t2*z2h + t3*z3).
__global__ void spmm_final_kernel(const int2* __restrict__ rowinfo,
                                  const int2* __restrict__ edges,
                                  const __half2* __restrict__ z2h2,
                                  const __half2* __restrict__ z1h2,
                                  const __half2* __restrict__ xh2,
                                  float* __restrict__ out,
                                  const float* __restrict__ gammas,
                                  float cA, float cC, int N) {
    __shared__ alignas(16) int2 lds[LDSE];   // 16 KB
    int t = threadIdx.x;
    int bid = blockIdx.x;
    int r0 = bid * 16;

    int gs = rowinfo[r0].x;
    int2 rlast = rowinfo[min(r0 + 15, N - 1)];
    int span = rlast.x + rlast.y - gs;
    if (span > LDSE) span = LDSE;
    {
        int n4 = span >> 1;
        const int4* s4 = (const int4*)(edges + gs);
        int4* d4 = (int4*)lds;
        for (int i = t; i < n4; i += 256) d4[i] = s4[i];
    }
    __syncthreads();

    int wv = t >> 6;
    int lane = t & 63;
    int q = lane >> 4;
    int k16 = lane & 15;
    int rr = r0 + wv * 4 + q;
    bool valid = rr < N;
    int r = valid ? rr : N - 1;

    float t0 = tanhf(gammas[0]) * 3.0f;
    float t1 = t0 * (tanhf(gammas[1]) * 3.0f);
    float t2 = t1 * (tanhf(gammas[2]) * 3.0f);
    float t3 = t2 * (tanhf(gammas[3]) * 3.0f);

    int2 ri = rowinfo[r];
    int cnt = __builtin_amdgcn_readfirstlane(ri.y);
    int off = ri.x - gs;
    if (off < 0 || off + cnt > span) off = 0;

    int boff = k16 * 8;
    size_t rb = (size_t)r * 128 + boff;
    // issue epilogue inputs early so their latency hides under the acc loop
    int2 pz1 = *(const int2*)((const char*)z1h2 + rb);
    int2 pz2 = *(const int2*)((const char*)z2h2 + rb);
    int2 pxv = *(const int2*)((const char*)xh2 + rb);

    __half2 acc0, acc1;
    quad_row_acc_lds(lds + off, cnt, (const char*)z2h2, boff, acc0, acc1);
    float2 a0 = __half22float2(acc0);
    float2 a1 = __half22float2(acc1);

    float2 z1v0 = __half22float2(*(__half2*)&pz1.x);
    float2 z1v1 = __half22float2(*(__half2*)&pz1.y);
    float2 z2v0 = __half22float2(*(__half2*)&pz2.x);
    float2 z2v1 = __half22float2(*(__half2*)&pz2.y);
    float2 xv0  = __half22float2(*(__half2*)&pxv.x);
    float2 xv1  = __half22float2(*(__half2*)&pxv.y);

    float2 z30 = make_float2(cA * a0.x + cC * z1v0.x, cA * a0.y + cC * z1v0.y);
    float2 z31 = make_float2(cA * a1.x + cC * z1v1.x, cA * a1.y + cC * z1v1.y);

    if (valid) {
        float4 o;
        o.x = 0.25f * (t0 * xv0.x + t1 * z1v0.x + t2 * z2v0.x + t3 * z30.x);
        o.y = 0.25f * (t0 * xv0.y + t1 * z1v0.y + t2 * z2v0.y + t3 * z30.y);
        o.z = 0.25f * (t0 * xv1.x + t1 * z1v1.x + t2 * z2v1.x + t3 * z31.x);
        o.w = 0.25f * (t0 * xv1.y + t1 * z1v1.y + t2 * z2v1.y + t3 * z31.y);
        ((float4*)out)[(size_t)r * 16 + k16] = o;
    }
}

extern "C" void kernel_launch(void* const* d_in, const int* in_sizes, int n_in,
                              void* d_out, int out_size, void* d_ws, size_t ws_size,
                              hipStream_t stream) {
    const float* x      = (const float*)d_in[0];
    const int*   ei     = (const int*)d_in[1];   // [2, E]: row then col
    const float* w      = (const float*)d_in[2];
    const float* gammas = (const float*)d_in[3]; // [L+1]

    const int E = in_sizes[1] / 2;
    const int N = in_sizes[0] / D;
    const long NF = (long)N * D;
    const int NB = (N + RB - 1) >> RB_SHIFT;

    float* out = (float*)d_out;

    // ws layout
    char* p = (char*)d_ws;
    __half* xh  = (__half*)p;       p += NF * sizeof(__half);
    __half* z1h = (__half*)p;       p += NF * sizeof(__half);
    __half* z2h = (__half*)p;       p += NF * sizeof(__half);
    int* rowcnt = (int*)p;          p += (size_t)N * sizeof(int);
    int* curs   = (int*)p;          p += (size_t)N * sizeof(int);
    p = (char*)(((uintptr_t)p + 15) & ~(uintptr_t)15);
    int2* rowinfo = (int2*)p;       p += (size_t)N * sizeof(int2);
    int2* edges = (int2*)p;         // NB * CAPE int2

    const int* row = ei;
    const int* col = ei + E;

    const double a = 1.0, b = 1.0;
    const int blk = 256;

    // ---- build quad-padded bucketed CSR directly + fp16 x ----
    hipMemsetAsync(rowcnt, 0, (size_t)N * sizeof(int), stream);
    hist_kernel<<<1024, blk, 0, stream>>>(row, rowcnt, E);
    scan_pad_kernel<<<NB, RB, 0, stream>>>(rowcnt, edges, rowinfo, curs, N);
    scatter_kernel<<<1024, blk, 0, stream>>>(row, col, w, curs, edges, E);
    tohalf_kernel<<<1024, blk, 0, stream>>>((const float4*)x, (ushort4*)xh, (int)(NF / 4));

    const int sgrid = (N + 15) / 16;              // 16 rows (4 waves) per 256-thread block

    // ---- l = 1: z1 = 2 * A x ----
    {
        float cA = (float)((a + b + 2.0) / 2.0);
        spmm_z_kernel<<<sgrid, blk, 0, stream>>>(rowinfo, edges, (const __half2*)xh,
                                                 nullptr, (__half2*)z1h, cA, 0.0f, N);
    }

    // ---- l = 2: z2 = (c2 A z1 - c3 x)/c0 ----
    {
        int l = 2;
        double c0 = 2.0 * l * (l + a + b) * (2.0 * l + a + b - 2.0);
        double c2 = (2.0 * l + a + b - 1.0) * (2.0 * l + a + b) * (2.0 * l + a + b - 2.0);
        double c3 = 2.0 * (l + a - 1.0) * (l + b - 1.0) * (2.0 * l + a + b);
        spmm_z_kernel<<<sgrid, blk, 0, stream>>>(rowinfo, edges, (const __half2*)z1h,
                                                 (const __half2*)xh, (__half2*)z2h,
                                                 (float)(c2 / c0), (float)(-c3 / c0), N);
    }

    // ---- l = 3 (fused final): z3 = (c2 A z2 - c3 z1)/c0 ; out = 0.25*sum coef_l z_l ----
    {
        int l = 3;
        double c0 = 2.0 * l * (l + a + b) * (2.0 * l + a + b - 2.0);
        double c2 = (2.0 * l + a + b - 1.0) * (2.0 * l + a + b) * (2.0 * l + a + b - 2.0);
        double c3 = 2.0 * (l + a - 1.0) * (l + b - 1.0) * (2.0 * l + a + b);
        spmm_final_kernel<<<sgrid, blk, 0, stream>>>(rowinfo, edges, (const __half2*)z2h,
                                                     (const __half2*)z1h, (const __half2*)xh,
                                                     out, gammas,
                                                     (float)(c2 / c0), (float)(-c3 / c0), N);
    }
}

// Round 4
// 202.580 us; speedup vs baseline: 1.5616x; 1.5616x over previous
//
#include <hip/hip_runtime.h>
#include <hip/hip_fp16.h>
#include <math.h>

#define D 64
#define RB_SHIFT 6          // 64 rows per bucket
#define RB 64
#define CAP 1024            // binned per-bucket capacity (mean ~800, sd ~28; +8 sigma)
#define CAPE 2048           // padded edges per bucket (expected ~1150)
#define MAX_NB 1600
#define LDSE 2048           // LDS desc stage: worst case = whole bucket (16 KB)

// ---------------- bucketed CSR build (fixed-capacity buckets) ----------------

// Block-aggregated two-pass scatter; 256 blocks x 1024 threads.
// Pack: x = col | (row_local << 17), y = w fp32 bits.
__global__ void bin_scatter_kernel(const int* __restrict__ row, const int* __restrict__ col,
                                   const float* __restrict__ w,
                                   int* __restrict__ cursor,
                                   int2* __restrict__ binned, int E, int NB) {
    __shared__ int lbase[MAX_NB];
    __shared__ int lcur[MAX_NB];
    int chunk = (E + gridDim.x - 1) / gridDim.x;
    int lo = blockIdx.x * chunk;
    int hi = min(E, lo + chunk);
    for (int j = threadIdx.x; j < NB; j += blockDim.x) { lbase[j] = 0; lcur[j] = 0; }
    __syncthreads();
    for (int i = lo + threadIdx.x; i < hi; i += blockDim.x)
        atomicAdd(&lbase[row[i] >> RB_SHIFT], 1);
    __syncthreads();
    for (int j = threadIdx.x; j < NB; j += blockDim.x) {
        int c = lbase[j];
        int base = c ? atomicAdd(&cursor[j], c) : 0;
        lbase[j] = j * CAP + base;
    }
    __syncthreads();
    for (int i = lo + threadIdx.x; i < hi; i += blockDim.x) {
        int r = row[i];
        int b = r >> RB_SHIFT;
        int off = atomicAdd(&lcur[b], 1);
        binned[lbase[b] + off] = make_int2(col[i] | ((r & (RB - 1)) << 17), __float_as_int(w[i]));
    }
}

// One workgroup (256 thr) per 64-row bucket.
// Rows are padded to a multiple of 4 AND to the max of their row-QUAD (rows
// 4m..4m+3) so the SpMM can run one row per 16-lane group with a wave-uniform
// loop bound. Desc emitted as x = col<<7 (byte offset of z row), y = w as
// duplicated-half2 bits. Emits rowinfo (start, padded_quad_len).
__global__ void bucket_sort_kernel(const int2* __restrict__ binned,
                                   const int* __restrict__ cursor,
                                   int2* __restrict__ edges, int2* __restrict__ rowinfo,
                                   int N, int NB) {
    __shared__ alignas(16) int2 perm[CAPE];   // 16 KB
    __shared__ int hist[RB];
    __shared__ int plr[RB];
    __shared__ int scn[RB];
    __shared__ int pst[RB];
    __shared__ int cur[RB];
    int b = blockIdx.x, t = threadIdx.x;
    int base = b * CAP;
    int cnt = cursor[b];
    if (cnt > CAP) cnt = CAP;

    if (t < RB) hist[t] = 0;
    __syncthreads();
    for (int i = t; i < cnt; i += 256)
        atomicAdd(&hist[(binned[base + i].x >> 17) & (RB - 1)], 1);
    __syncthreads();
    if (t < RB) plr[t] = (hist[t] + 3) & ~3;           // row padded length (mult of 4)
    __syncthreads();
    if (t < RB) {                                      // quad-common padded length
        int qb = t & ~3;
        scn[t] = max(max(plr[qb], plr[qb | 1]), max(plr[qb | 2], plr[qb | 3]));
    }
    __syncthreads();
    for (int off = 1; off < RB; off <<= 1) {           // inclusive scan
        int v = (t < RB && t >= off) ? scn[t - off] : 0;
        __syncthreads();
        if (t < RB) scn[t] += v;
        __syncthreads();
    }
    if (t < RB) {
        int qb = t & ~3;
        int pl = max(max(plr[qb], plr[qb | 1]), max(plr[qb | 2], plr[qb | 3]));
        int ps = scn[t] - pl;                          // padded exclusive start (mult of 4)
        pst[t] = ps;
        cur[t] = ps;
    }
    __syncthreads();
    for (int i = t; i < cnt; i += 256) {               // placement (L2-hot re-read)
        int2 e = binned[base + i];
        int rl = (e.x >> 17) & (RB - 1);
        int d = atomicAdd(&cur[rl], 1);
        __half2 wh2 = __half2half2(__float2half(__int_as_float(e.y)));
        perm[d] = make_int2((e.x & 0x1FFFF) << 7, *(int*)&wh2);
    }
    __syncthreads();
    if (t < RB) {                                      // pad fill + rowinfo
        int h = hist[t];
        int ps = pst[t];
        int qb = t & ~3;
        int pl = max(max(plr[qb], plr[qb | 1]), max(plr[qb | 2], plr[qb | 3]));
        int dummycol = (h > 0) ? perm[ps].x : 0;       // valid byte offset (node 0 ok)
        for (int i = h; i < pl; ++i) perm[ps + i] = make_int2(dummycol, 0);  // w = 0
        int r0 = b * RB + t;
        if (r0 < N) rowinfo[r0] = make_int2(b * CAPE + ps, pl);
    }
    __syncthreads();
    int ptotal = scn[RB - 1];                          // expected ~1150 << CAPE
    if (ptotal > CAPE) ptotal = CAPE;
    // ptotal is a multiple of 4 descs -> copy as int4 (16 B)
    int n4 = ptotal >> 1;
    const int4* ps4 = (const int4*)perm;
    int4* pd4 = (int4*)(edges + (size_t)b * CAPE);
    for (int i = t; i < n4; i += 256) pd4[i] = ps4[i];
}

// fp32 -> fp16 convert (vectorized)
__global__ void tohalf_kernel(const float4* __restrict__ in, ushort4* __restrict__ o, int n4) {
    int i = blockIdx.x * blockDim.x + threadIdx.x;
    int stride = gridDim.x * blockDim.x;
    for (; i < n4; i += stride) {
        float4 f = in[i];
        ushort4 h;
        h.x = __half_as_ushort(__float2half(f.x));
        h.y = __half_as_ushort(__float2half(f.y));
        h.z = __half_as_ushort(__float2half(f.z));
        h.w = __half_as_ushort(__float2half(f.w));
        o[i] = h;
    }
}

// ---- per-16-lane-group row gather-accumulate, software-pipelined depth 2 ----
// Wave = 4 rows (one per 16-lane group); lane k16 owns features [4k16, 4k16+4)
// = 8 bytes of the z row. The next chunk's descs + gathers are ISSUED before
// the current chunk's hfma2s consume their data -> 8 gathers outstanding per
// group (32 lines/wave) instead of 4, doubling latency cover. FMA order is
// unchanged vs the non-pipelined version (bit-identical result).
__device__ __forceinline__ void quad_row_acc_lds(const int2* __restrict__ lds_desc, int cnt,
                                                 const char* __restrict__ g2b, int boff,
                                                 __half2& acc0, __half2& acc1) {
    acc0 = __half2half2(__ushort_as_half((unsigned short)0));
    acc1 = acc0;
    if (cnt <= 0) return;
    const int4* p4 = (const int4*)lds_desc;
    int4 d0 = p4[0];
    int4 d1 = p4[1];
    int2 g0 = *(const int2*)(g2b + (size_t)(unsigned)(d0.x + boff));
    int2 g1 = *(const int2*)(g2b + (size_t)(unsigned)(d0.z + boff));
    int2 g2 = *(const int2*)(g2b + (size_t)(unsigned)(d1.x + boff));
    int2 g3 = *(const int2*)(g2b + (size_t)(unsigned)(d1.z + boff));
    for (int jb = 4; jb < cnt; jb += 4) {
        // issue next chunk (descs from LDS, gathers from global) BEFORE
        // consuming the current chunk
        int4 nd0 = p4[jb >> 1];
        int4 nd1 = p4[(jb >> 1) + 1];
        int2 n0 = *(const int2*)(g2b + (size_t)(unsigned)(nd0.x + boff));
        int2 n1 = *(const int2*)(g2b + (size_t)(unsigned)(nd0.z + boff));
        int2 n2 = *(const int2*)(g2b + (size_t)(unsigned)(nd1.x + boff));
        int2 n3 = *(const int2*)(g2b + (size_t)(unsigned)(nd1.z + boff));
        acc0 = __hfma2(*(__half2*)&d0.y, *(__half2*)&g0.x, acc0);
        acc1 = __hfma2(*(__half2*)&d0.y, *(__half2*)&g0.y, acc1);
        acc0 = __hfma2(*(__half2*)&d0.w, *(__half2*)&g1.x, acc0);
        acc1 = __hfma2(*(__half2*)&d0.w, *(__half2*)&g1.y, acc1);
        acc0 = __hfma2(*(__half2*)&d1.y, *(__half2*)&g2.x, acc0);
        acc1 = __hfma2(*(__half2*)&d1.y, *(__half2*)&g2.y, acc1);
        acc0 = __hfma2(*(__half2*)&d1.w, *(__half2*)&g3.x, acc0);
        acc1 = __hfma2(*(__half2*)&d1.w, *(__half2*)&g3.y, acc1);
        d0 = nd0; d1 = nd1;
        g0 = n0; g1 = n1; g2 = n2; g3 = n3;
    }
    // drain last chunk
    acc0 = __hfma2(*(__half2*)&d0.y, *(__half2*)&g0.x, acc0);
    acc1 = __hfma2(*(__half2*)&d0.y, *(__half2*)&g0.y, acc1);
    acc0 = __hfma2(*(__half2*)&d0.w, *(__half2*)&g1.x, acc0);
    acc1 = __hfma2(*(__half2*)&d0.w, *(__half2*)&g1.y, acc1);
    acc0 = __hfma2(*(__half2*)&d1.y, *(__half2*)&g2.x, acc0);
    acc1 = __hfma2(*(__half2*)&d1.y, *(__half2*)&g2.y, acc1);
    acc0 = __hfma2(*(__half2*)&d1.w, *(__half2*)&g3.x, acc0);
    acc1 = __hfma2(*(__half2*)&d1.w, *(__half2*)&g3.y, acc1);
}

// ---------------- SpMM z-producer: z = cA * (A gsrc) + cC * zp2 ----------------
// One block = 4 waves = 16 consecutive rows (inside one 64-row bucket, so
// their descs are one contiguous span in edges). Stage span -> LDS, then one
// wave = 4 rows (one per 16-lane group).
__global__ void spmm_z_kernel(const int2* __restrict__ rowinfo,
                              const int2* __restrict__ edges,
                              const __half2* __restrict__ gsrc2,
                              const __half2* __restrict__ zp2_2,   // may be null
                              __half2* __restrict__ zdst2,
                              float cA, float cC, int N) {
    __shared__ alignas(16) int2 lds[LDSE];   // 16 KB
    int t = threadIdx.x;
    int bid = blockIdx.x;
    int r0 = bid * 16;

    // block-uniform desc span (contiguous by bucket_sort construction)
    int gs = rowinfo[r0].x;
    int2 rlast = rowinfo[min(r0 + 15, N - 1)];
    int span = rlast.x + rlast.y - gs;
    if (span > LDSE) span = LDSE;                      // pathological-skew guard
    {   // span and gs are multiples of 4 descs -> int4 staging
        int n4 = span >> 1;
        const int4* s4 = (const int4*)(edges + gs);
        int4* d4 = (int4*)lds;
        for (int i = t; i < n4; i += 256) d4[i] = s4[i];
    }
    __syncthreads();

    int wv = t >> 6;
    int lane = t & 63;
    int q = lane >> 4;
    int k16 = lane & 15;
    int rr = r0 + wv * 4 + q;
    bool valid = rr < N;
    int r = valid ? rr : N - 1;

    int2 ri = rowinfo[r];
    int cnt = __builtin_amdgcn_readfirstlane(ri.y);   // quad-common length
    int off = ri.x - gs;
    if (off < 0 || off + cnt > span) off = 0;         // safety

    int boff = k16 * 8;                                // byte offset within z row
    size_t rb = (size_t)r * 128 + boff;
    // issue epilogue input early so its latency hides under the acc loop
    float2 p0 = make_float2(0.f, 0.f), p1 = p0;
    if (zp2_2) {
        int2 pz = *(const int2*)((const char*)zp2_2 + rb);
        p0 = __half22float2(*(__half2*)&pz.x);
        p1 = __half22float2(*(__half2*)&pz.y);
    }

    __half2 acc0, acc1;
    quad_row_acc_lds(lds + off, cnt, (const char*)gsrc2, boff, acc0, acc1);
    float2 a0 = __half22float2(acc0);
    float2 a1 = __half22float2(acc1);

    float2 z0 = make_float2(cA * a0.x, cA * a0.y);
    float2 z1 = make_float2(cA * a1.x, cA * a1.y);
    if (zp2_2) {
        z0.x = fmaf(cC, p0.x, z0.x); z0.y = fmaf(cC, p0.y, z0.y);
        z1.x = fmaf(cC, p1.x, z1.x); z1.y = fmaf(cC, p1.y, z1.y);
    }
    if (valid) {
        __half2 h0 = __floats2half2_rn(z0.x, z0.y);
        __half2 h1 = __floats2half2_rn(z1.x, z1.y);
        int2 st;
        st.x = *(int*)&h0;
        st.y = *(int*)&h1;
        *(int2*)((char*)zdst2 + rb) = st;
    }
}

// ---------------- final SpMM + full output reduction ----------------
// z3 = cA*(A z2h) + cC*z1h (in-register);
// out = 0.25*(t0*xh + t1*z1h + t2*z2h + t3*z3).
__global__ void spmm_final_kernel(const int2* __restrict__ rowinfo,
                                  const int2* __restrict__ edges,
                                  const __half2* __restrict__ z2h2,
                                  const __half2* __restrict__ z1h2,
                                  const __half2* __restrict__ xh2,
                                  float* __restrict__ out,
                                  const float* __restrict__ gammas,
                                  float cA, float cC, int N) {
    __shared__ alignas(16) int2 lds[LDSE];   // 16 KB
    int t = threadIdx.x;
    int bid = blockIdx.x;
    int r0 = bid * 16;

    int gs = rowinfo[r0].x;
    int2 rlast = rowinfo[min(r0 + 15, N - 1)];
    int span = rlast.x + rlast.y - gs;
    if (span > LDSE) span = LDSE;
    {
        int n4 = span >> 1;
        const int4* s4 = (const int4*)(edges + gs);
        int4* d4 = (int4*)lds;
        for (int i = t; i < n4; i += 256) d4[i] = s4[i];
    }
    __syncthreads();

    int wv = t >> 6;
    int lane = t & 63;
    int q = lane >> 4;
    int k16 = lane & 15;
    int rr = r0 + wv * 4 + q;
    bool valid = rr < N;
    int r = valid ? rr : N - 1;

    float t0 = tanhf(gammas[0]) * 3.0f;
    float t1 = t0 * (tanhf(gammas[1]) * 3.0f);
    float t2 = t1 * (tanhf(gammas[2]) * 3.0f);
    float t3 = t2 * (tanhf(gammas[3]) * 3.0f);

    int2 ri = rowinfo[r];
    int cnt = __builtin_amdgcn_readfirstlane(ri.y);
    int off = ri.x - gs;
    if (off < 0 || off + cnt > span) off = 0;

    int boff = k16 * 8;
    size_t rb = (size_t)r * 128 + boff;
    // issue epilogue inputs early so their latency hides under the acc loop
    int2 pz1 = *(const int2*)((const char*)z1h2 + rb);
    int2 pz2 = *(const int2*)((const char*)z2h2 + rb);
    int2 pxv = *(const int2*)((const char*)xh2 + rb);

    __half2 acc0, acc1;
    quad_row_acc_lds(lds + off, cnt, (const char*)z2h2, boff, acc0, acc1);
    float2 a0 = __half22float2(acc0);
    float2 a1 = __half22float2(acc1);

    float2 z1v0 = __half22float2(*(__half2*)&pz1.x);
    float2 z1v1 = __half22float2(*(__half2*)&pz1.y);
    float2 z2v0 = __half22float2(*(__half2*)&pz2.x);
    float2 z2v1 = __half22float2(*(__half2*)&pz2.y);
    float2 xv0  = __half22float2(*(__half2*)&pxv.x);
    float2 xv1  = __half22float2(*(__half2*)&pxv.y);

    float2 z30 = make_float2(cA * a0.x + cC * z1v0.x, cA * a0.y + cC * z1v0.y);
    float2 z31 = make_float2(cA * a1.x + cC * z1v1.x, cA * a1.y + cC * z1v1.y);

    if (valid) {
        float4 o;
        o.x = 0.25f * (t0 * xv0.x + t1 * z1v0.x + t2 * z2v0.x + t3 * z30.x);
        o.y = 0.25f * (t0 * xv0.y + t1 * z1v0.y + t2 * z2v0.y + t3 * z30.y);
        o.z = 0.25f * (t0 * xv1.x + t1 * z1v1.x + t2 * z2v1.x + t3 * z31.x);
        o.w = 0.25f * (t0 * xv1.y + t1 * z1v1.y + t2 * z2v1.y + t3 * z31.y);
        ((float4*)out)[(size_t)r * 16 + k16] = o;
    }
}

extern "C" void kernel_launch(void* const* d_in, const int* in_sizes, int n_in,
                              void* d_out, int out_size, void* d_ws, size_t ws_size,
                              hipStream_t stream) {
    const float* x      = (const float*)d_in[0];
    const int*   ei     = (const int*)d_in[1];   // [2, E]: row then col
    const float* w      = (const float*)d_in[2];
    const float* gammas = (const float*)d_in[3]; // [L+1]

    const int E = in_sizes[1] / 2;
    const int N = in_sizes[0] / D;
    const long NF = (long)N * D;
    const int NB = (N + RB - 1) >> RB_SHIFT;

    float* out = (float*)d_out;

    // ws layout
    char* p = (char*)d_ws;
    __half* xh  = (__half*)p;       p += NF * sizeof(__half);
    __half* z1h = (__half*)p;       p += NF * sizeof(__half);
    __half* z2h = (__half*)p;       p += NF * sizeof(__half);
    int* cursor = (int*)p;          p += NB * sizeof(int);
    p = (char*)(((uintptr_t)p + 15) & ~(uintptr_t)15);
    int2* rowinfo = (int2*)p;       p += (size_t)N * sizeof(int2);
    int2* binned = (int2*)p;        p += (size_t)NB * CAP * sizeof(int2);
    int2* edges = (int2*)p;         // NB * CAPE int2

    const int* row = ei;
    const int* col = ei + E;

    const double a = 1.0, b = 1.0;
    const int blk = 256;

    // ---- build bucketed, quad-padded CSR + fp16 x ----
    hipMemsetAsync(cursor, 0, (size_t)NB * sizeof(int), stream);
    bin_scatter_kernel<<<256, 1024, 0, stream>>>(row, col, w, cursor, binned, E, NB);
    bucket_sort_kernel<<<NB, 256, 0, stream>>>(binned, cursor, edges, rowinfo, N, NB);
    tohalf_kernel<<<1024, blk, 0, stream>>>((const float4*)x, (ushort4*)xh, (int)(NF / 4));

    const int sgrid = (N + 15) / 16;              // 16 rows (4 waves) per 256-thread block

    // ---- l = 1: z1 = 2 * A x ----
    {
        float cA = (float)((a + b + 2.0) / 2.0);
        spmm_z_kernel<<<sgrid, blk, 0, stream>>>(rowinfo, edges, (const __half2*)xh,
                                                 nullptr, (__half2*)z1h, cA, 0.0f, N);
    }

    // ---- l = 2: z2 = (c2 A z1 - c3 x)/c0 ----
    {
        int l = 2;
        double c0 = 2.0 * l * (l + a + b) * (2.0 * l + a + b - 2.0);
        double c2 = (2.0 * l + a + b - 1.0) * (2.0 * l + a + b) * (2.0 * l + a + b - 2.0);
        double c3 = 2.0 * (l + a - 1.0) * (l + b - 1.0) * (2.0 * l + a + b);
        spmm_z_kernel<<<sgrid, blk, 0, stream>>>(rowinfo, edges, (const __half2*)z1h,
                                                 (const __half2*)xh, (__half2*)z2h,
                                                 (float)(c2 / c0), (float)(-c3 / c0), N);
    }

    // ---- l = 3 (fused final): z3 = (c2 A z2 - c3 z1)/c0 ; out = 0.25*sum coef_l z_l ----
    {
        int l = 3;
        double c0 = 2.0 * l * (l + a + b) * (2.0 * l + a + b - 2.0);
        double c2 = (2.0 * l + a + b - 1.0) * (2.0 * l + a + b) * (2.0 * l + a + b - 2.0);
        double c3 = 2.0 * (l + a - 1.0) * (l + b - 1.0) * (2.0 * l + a + b);
        spmm_final_kernel<<<sgrid, blk, 0, stream>>>(rowinfo, edges, (const __half2*)z2h,
                                                     (const __half2*)z1h, (const __half2*)xh,
                                                     out, gammas,
                                                     (float)(c2 / c0), (float)(-c3 / c0), N);
    }
}

// Round 5
// 195.212 us; speedup vs baseline: 1.6205x; 1.0377x over previous
//
#include <hip/hip_runtime.h>
#include <hip/hip_fp16.h>
#include <math.h>

#define D 64
#define RB_SHIFT 6          // 64 rows per bucket
#define RB 64
#define CAP 1024            // binned per-bucket capacity (mean ~800, sd ~28; +8 sigma)
#define CAPE 2048           // padded edges per bucket (expected ~1150)
#define MAX_NB 1600
#define LDSE 2048           // LDS desc stage: worst case = whole bucket (16 KB)

// ---------------- build pass 1: bucket scatter + fused x->fp16 ----------------

// Block-aggregated two-pass scatter; 256 blocks x 1024 threads.
// Pack: x = col | (row_local << 17), y = w fp32 bits.
// Fused at the end: grid-stride fp32->fp16 convert of x (independent work,
// overlaps the BW-bound convert with the atomic-bound scatter; -1 dispatch).
__global__ void bin_scatter_tohalf_kernel(const int* __restrict__ row, const int* __restrict__ col,
                                          const float* __restrict__ w,
                                          int* __restrict__ cursor,
                                          int2* __restrict__ binned, int E, int NB,
                                          const float4* __restrict__ xin,
                                          ushort4* __restrict__ xh4, int n4) {
    __shared__ int lbase[MAX_NB];
    __shared__ int lcur[MAX_NB];
    int chunk = (E + gridDim.x - 1) / gridDim.x;
    int lo = blockIdx.x * chunk;
    int hi = min(E, lo + chunk);
    for (int j = threadIdx.x; j < NB; j += blockDim.x) { lbase[j] = 0; lcur[j] = 0; }
    __syncthreads();
    for (int i = lo + threadIdx.x; i < hi; i += blockDim.x)
        atomicAdd(&lbase[row[i] >> RB_SHIFT], 1);
    __syncthreads();
    for (int j = threadIdx.x; j < NB; j += blockDim.x) {
        int c = lbase[j];
        int base = c ? atomicAdd(&cursor[j], c) : 0;
        lbase[j] = j * CAP + base;
    }
    __syncthreads();
    for (int i = lo + threadIdx.x; i < hi; i += blockDim.x) {
        int r = row[i];
        int b = r >> RB_SHIFT;
        int off = atomicAdd(&lcur[b], 1);
        binned[lbase[b] + off] = make_int2(col[i] | ((r & (RB - 1)) << 17), __float_as_int(w[i]));
    }
    // fused tohalf (no barrier needed; independent of the scatter)
    int gtid = blockIdx.x * blockDim.x + threadIdx.x;
    int gstride = gridDim.x * blockDim.x;
    for (int i = gtid; i < n4; i += gstride) {
        float4 f = xin[i];
        ushort4 h;
        h.x = __half_as_ushort(__float2half(f.x));
        h.y = __half_as_ushort(__float2half(f.y));
        h.z = __half_as_ushort(__float2half(f.z));
        h.w = __half_as_ushort(__float2half(f.w));
        xh4[i] = h;
    }
}

// ---- per-16-lane-group row gather-accumulate (simple round-2 loop) ----
// Wave = 4 rows (one per 16-lane group); lane k16 owns features [4k16, 4k16+4)
// = 8 bytes of the z row. Per chunk of 4 edges: 2x ds_read_b128 (4 descs,
// broadcast within group) + 4x dwordx2 gather (64 lanes x 8 B = 512 B = 4
// fully-used cache lines) + 8x hfma2.
__device__ __forceinline__ void quad_row_acc_lds(const int2* __restrict__ lds_desc, int cnt,
                                                 const char* __restrict__ g2b, int boff,
                                                 __half2& acc0, __half2& acc1) {
    acc0 = __half2half2(__ushort_as_half((unsigned short)0));
    acc1 = acc0;
    for (int jb = 0; jb < cnt; jb += 4) {
        const int4* p4 = (const int4*)(lds_desc + jb);
        int4 d0 = p4[0];
        int4 d1 = p4[1];
        int2 g0 = *(const int2*)(g2b + (size_t)(unsigned)(d0.x + boff));
        int2 g1 = *(const int2*)(g2b + (size_t)(unsigned)(d0.z + boff));
        int2 g2 = *(const int2*)(g2b + (size_t)(unsigned)(d1.x + boff));
        int2 g3 = *(const int2*)(g2b + (size_t)(unsigned)(d1.z + boff));
        acc0 = __hfma2(*(__half2*)&d0.y, *(__half2*)&g0.x, acc0);
        acc1 = __hfma2(*(__half2*)&d0.y, *(__half2*)&g0.y, acc1);
        acc0 = __hfma2(*(__half2*)&d0.w, *(__half2*)&g1.x, acc0);
        acc1 = __hfma2(*(__half2*)&d0.w, *(__half2*)&g1.y, acc1);
        acc0 = __hfma2(*(__half2*)&d1.y, *(__half2*)&g2.x, acc0);
        acc1 = __hfma2(*(__half2*)&d1.y, *(__half2*)&g2.y, acc1);
        acc0 = __hfma2(*(__half2*)&d1.w, *(__half2*)&g3.x, acc0);
        acc1 = __hfma2(*(__half2*)&d1.w, *(__half2*)&g3.y, acc1);
    }
}

// ---------------- build pass 2 FUSED with SpMM l=1 ----------------
// One workgroup (256 thr) per 64-row bucket. Builds the quad-padded desc list
// in LDS (perm), writes edges/rowinfo to global for phases l=2/3, then runs
// the l=1 SpMM (z1 = cA * A x) for its 64 rows DIRECTLY from the LDS descs:
// 4 passes, each pass = 4 waves x 4 rows (one quad per wave -> wave-uniform
// cnt). Eliminates spmm1's 11.4 MB edge re-read + LDS restage + rowinfo reads
// + one dispatch. FMA order per row identical to the split version.
__global__ void bucket_sort_spmm1_kernel(const int2* __restrict__ binned,
                                         const int* __restrict__ cursor,
                                         int2* __restrict__ edges, int2* __restrict__ rowinfo,
                                         const __half2* __restrict__ xh2,
                                         __half2* __restrict__ z1h2,
                                         float cA, int N, int NB) {
    __shared__ alignas(16) int2 perm[CAPE];   // 16 KB
    __shared__ int hist[RB];
    __shared__ int plr[RB];
    __shared__ int scn[RB];
    __shared__ int pst[RB];
    __shared__ int cur[RB];
    __shared__ int plc[RB];
    int b = blockIdx.x, t = threadIdx.x;
    int base = b * CAP;
    int cnt = cursor[b];
    if (cnt > CAP) cnt = CAP;

    if (t < RB) hist[t] = 0;
    __syncthreads();
    for (int i = t; i < cnt; i += 256)
        atomicAdd(&hist[(binned[base + i].x >> 17) & (RB - 1)], 1);
    __syncthreads();
    if (t < RB) plr[t] = (hist[t] + 3) & ~3;           // row padded length (mult of 4)
    __syncthreads();
    if (t < RB) {                                      // quad-common padded length
        int qb = t & ~3;
        scn[t] = max(max(plr[qb], plr[qb | 1]), max(plr[qb | 2], plr[qb | 3]));
    }
    __syncthreads();
    for (int off = 1; off < RB; off <<= 1) {           // inclusive scan
        int v = (t < RB && t >= off) ? scn[t - off] : 0;
        __syncthreads();
        if (t < RB) scn[t] += v;
        __syncthreads();
    }
    if (t < RB) {
        int qb = t & ~3;
        int pl = max(max(plr[qb], plr[qb | 1]), max(plr[qb | 2], plr[qb | 3]));
        int ps = scn[t] - pl;                          // padded exclusive start (mult of 4)
        pst[t] = ps;
        cur[t] = ps;
        plc[t] = pl;
    }
    __syncthreads();
    for (int i = t; i < cnt; i += 256) {               // placement (L2-hot re-read)
        int2 e = binned[base + i];
        int rl = (e.x >> 17) & (RB - 1);
        int d = atomicAdd(&cur[rl], 1);
        __half2 wh2 = __half2half2(__float2half(__int_as_float(e.y)));
        perm[d] = make_int2((e.x & 0x1FFFF) << 7, *(int*)&wh2);
    }
    __syncthreads();
    if (t < RB) {                                      // pad fill + rowinfo
        int h = hist[t];
        int ps = pst[t];
        int pl = plc[t];
        int dummycol = (h > 0) ? perm[ps].x : 0;       // valid byte offset (node 0 ok)
        for (int i = h; i < pl; ++i) perm[ps + i] = make_int2(dummycol, 0);  // w = 0
        int r0 = b * RB + t;
        if (r0 < N) rowinfo[r0] = make_int2(b * CAPE + ps, pl);
    }
    __syncthreads();
    {   // copy-out for phases l=2/3 (multiple of 4 descs -> int4, 16 B)
        int ptotal = scn[RB - 1];                      // expected ~1150 << CAPE
        if (ptotal > CAPE) ptotal = CAPE;
        int n4 = ptotal >> 1;
        const int4* ps4 = (const int4*)perm;
        int4* pd4 = (int4*)(edges + (size_t)b * CAPE);
        for (int i = t; i < n4; i += 256) pd4[i] = ps4[i];
    }

    // ---- SpMM l=1 straight from LDS descs: z1 = cA * (A x) ----
    int w = t >> 6;
    int lane = t & 63;
    int q = lane >> 4;
    int k16 = lane & 15;
    int boff = k16 * 8;
    for (int p = 0; p < 4; ++p) {
        int qi = p * 4 + w;                            // quad index (wave-uniform)
        int lr = qi * 4 + q;                           // local row in bucket
        int r = b * RB + lr;
        int ccnt = __builtin_amdgcn_readfirstlane(plc[qi * 4]);  // quad-common length
        int off = pst[lr];
        __half2 acc0, acc1;
        quad_row_acc_lds(perm + off, ccnt, (const char*)xh2, boff, acc0, acc1);
        float2 a0 = __half22float2(acc0);
        float2 a1 = __half22float2(acc1);
        if (r < N) {
            __half2 h0 = __floats2half2_rn(cA * a0.x, cA * a0.y);
            __half2 h1 = __floats2half2_rn(cA * a1.x, cA * a1.y);
            int2 st;
            st.x = *(int*)&h0;
            st.y = *(int*)&h1;
            *(int2*)((char*)z1h2 + (size_t)r * 128 + boff) = st;
        }
    }
}

// ---------------- SpMM z-producer (l=2): z2 = cA * (A z1) + cC * x ----------------
// One block = 4 waves = 16 consecutive rows (inside one 64-row bucket, so
// their descs are one contiguous span in edges). Stage span -> LDS, then one
// wave = 4 rows (one per 16-lane group).
__global__ void spmm_z_kernel(const int2* __restrict__ rowinfo,
                              const int2* __restrict__ edges,
                              const __half2* __restrict__ gsrc2,
                              const __half2* __restrict__ zp2_2,
                              __half2* __restrict__ zdst2,
                              float cA, float cC, int N) {
    __shared__ alignas(16) int2 lds[LDSE];   // 16 KB
    int t = threadIdx.x;
    int bid = blockIdx.x;
    int r0 = bid * 16;

    // block-uniform desc span (contiguous by construction)
    int gs = rowinfo[r0].x;
    int2 rlast = rowinfo[min(r0 + 15, N - 1)];
    int span = rlast.x + rlast.y - gs;
    if (span > LDSE) span = LDSE;                      // pathological-skew guard
    {   // span and gs are multiples of 4 descs -> int4 staging
        int n4 = span >> 1;
        const int4* s4 = (const int4*)(edges + gs);
        int4* d4 = (int4*)lds;
        for (int i = t; i < n4; i += 256) d4[i] = s4[i];
    }
    __syncthreads();

    int wv = t >> 6;
    int lane = t & 63;
    int q = lane >> 4;
    int k16 = lane & 15;
    int rr = r0 + wv * 4 + q;
    bool valid = rr < N;
    int r = valid ? rr : N - 1;

    int2 ri = rowinfo[r];
    int cnt = __builtin_amdgcn_readfirstlane(ri.y);   // quad-common length
    int off = ri.x - gs;
    if (off < 0 || off + cnt > span) off = 0;         // safety

    int boff = k16 * 8;                                // byte offset within z row
    size_t rb = (size_t)r * 128 + boff;
    // issue epilogue input early so its latency hides under the acc loop
    int2 pz = *(const int2*)((const char*)zp2_2 + rb);
    float2 p0 = __half22float2(*(__half2*)&pz.x);
    float2 p1 = __half22float2(*(__half2*)&pz.y);

    __half2 acc0, acc1;
    quad_row_acc_lds(lds + off, cnt, (const char*)gsrc2, boff, acc0, acc1);
    float2 a0 = __half22float2(acc0);
    float2 a1 = __half22float2(acc1);

    float2 z0 = make_float2(fmaf(cC, p0.x, cA * a0.x), fmaf(cC, p0.y, cA * a0.y));
    float2 z1 = make_float2(fmaf(cC, p1.x, cA * a1.x), fmaf(cC, p1.y, cA * a1.y));
    if (valid) {
        __half2 h0 = __floats2half2_rn(z0.x, z0.y);
        __half2 h1 = __floats2half2_rn(z1.x, z1.y);
        int2 st;
        st.x = *(int*)&h0;
        st.y = *(int*)&h1;
        *(int2*)((char*)zdst2 + rb) = st;
    }
}

// ---------------- final SpMM + full output reduction ----------------
// z3 = cA*(A z2h) + cC*z1h (in-register);
// out = 0.25*(t0*xh + t1*z1h + t2*z2h + t3*z3).
__global__ void spmm_final_kernel(const int2* __restrict__ rowinfo,
                                  const int2* __restrict__ edges,
                                  const __half2* __restrict__ z2h2,
                                  const __half2* __restrict__ z1h2,
                                  const __half2* __restrict__ xh2,
                                  float* __restrict__ out,
                                  const float* __restrict__ gammas,
                                  float cA, float cC, int N) {
    __shared__ alignas(16) int2 lds[LDSE];   // 16 KB
    int t = threadIdx.x;
    int bid = blockIdx.x;
    int r0 = bid * 16;

    int gs = rowinfo[r0].x;
    int2 rlast = rowinfo[min(r0 + 15, N - 1)];
    int span = rlast.x + rlast.y - gs;
    if (span > LDSE) span = LDSE;
    {
        int n4 = span >> 1;
        const int4* s4 = (const int4*)(edges + gs);
        int4* d4 = (int4*)lds;
        for (int i = t; i < n4; i += 256) d4[i] = s4[i];
    }
    __syncthreads();

    int wv = t >> 6;
    int lane = t & 63;
    int q = lane >> 4;
    int k16 = lane & 15;
    int rr = r0 + wv * 4 + q;
    bool valid = rr < N;
    int r = valid ? rr : N - 1;

    float t0 = tanhf(gammas[0]) * 3.0f;
    float t1 = t0 * (tanhf(gammas[1]) * 3.0f);
    float t2 = t1 * (tanhf(gammas[2]) * 3.0f);
    float t3 = t2 * (tanhf(gammas[3]) * 3.0f);

    int2 ri = rowinfo[r];
    int cnt = __builtin_amdgcn_readfirstlane(ri.y);
    int off = ri.x - gs;
    if (off < 0 || off + cnt > span) off = 0;

    int boff = k16 * 8;
    size_t rb = (size_t)r * 128 + boff;
    // issue epilogue inputs early so their latency hides under the acc loop
    int2 pz1 = *(const int2*)((const char*)z1h2 + rb);
    int2 pz2 = *(const int2*)((const char*)z2h2 + rb);
    int2 pxv = *(const int2*)((const char*)xh2 + rb);

    __half2 acc0, acc1;
    quad_row_acc_lds(lds + off, cnt, (const char*)z2h2, boff, acc0, acc1);
    float2 a0 = __half22float2(acc0);
    float2 a1 = __half22float2(acc1);

    float2 z1v0 = __half22float2(*(__half2*)&pz1.x);
    float2 z1v1 = __half22float2(*(__half2*)&pz1.y);
    float2 z2v0 = __half22float2(*(__half2*)&pz2.x);
    float2 z2v1 = __half22float2(*(__half2*)&pz2.y);
    float2 xv0  = __half22float2(*(__half2*)&pxv.x);
    float2 xv1  = __half22float2(*(__half2*)&pxv.y);

    float2 z30 = make_float2(cA * a0.x + cC * z1v0.x, cA * a0.y + cC * z1v0.y);
    float2 z31 = make_float2(cA * a1.x + cC * z1v1.x, cA * a1.y + cC * z1v1.y);

    if (valid) {
        float4 o;
        o.x = 0.25f * (t0 * xv0.x + t1 * z1v0.x + t2 * z2v0.x + t3 * z30.x);
        o.y = 0.25f * (t0 * xv0.y + t1 * z1v0.y + t2 * z2v0.y + t3 * z30.y);
        o.z = 0.25f * (t0 * xv1.x + t1 * z1v1.x + t2 * z2v1.x + t3 * z31.x);
        o.w = 0.25f * (t0 * xv1.y + t1 * z1v1.y + t2 * z2v1.y + t3 * z31.y);
        ((float4*)out)[(size_t)r * 16 + k16] = o;
    }
}

extern "C" void kernel_launch(void* const* d_in, const int* in_sizes, int n_in,
                              void* d_out, int out_size, void* d_ws, size_t ws_size,
                              hipStream_t stream) {
    const float* x      = (const float*)d_in[0];
    const int*   ei     = (const int*)d_in[1];   // [2, E]: row then col
    const float* w      = (const float*)d_in[2];
    const float* gammas = (const float*)d_in[3]; // [L+1]

    const int E = in_sizes[1] / 2;
    const int N = in_sizes[0] / D;
    const long NF = (long)N * D;
    const int NB = (N + RB - 1) >> RB_SHIFT;

    float* out = (float*)d_out;

    // ws layout
    char* p = (char*)d_ws;
    __half* xh  = (__half*)p;       p += NF * sizeof(__half);
    __half* z1h = (__half*)p;       p += NF * sizeof(__half);
    __half* z2h = (__half*)p;       p += NF * sizeof(__half);
    int* cursor = (int*)p;          p += NB * sizeof(int);
    p = (char*)(((uintptr_t)p + 15) & ~(uintptr_t)15);
    int2* rowinfo = (int2*)p;       p += (size_t)N * sizeof(int2);
    int2* binned = (int2*)p;        p += (size_t)NB * CAP * sizeof(int2);
    int2* edges = (int2*)p;         // NB * CAPE int2

    const int* row = ei;
    const int* col = ei + E;

    const double a = 1.0, b = 1.0;
    const int blk = 256;

    // ---- 4 dispatches total ----
    hipMemsetAsync(cursor, 0, (size_t)NB * sizeof(int), stream);
    bin_scatter_tohalf_kernel<<<256, 1024, 0, stream>>>(row, col, w, cursor, binned, E, NB,
                                                        (const float4*)x, (ushort4*)xh,
                                                        (int)(NF / 4));

    // build + l=1 fused: z1 = 2 * A x
    {
        float cA = (float)((a + b + 2.0) / 2.0);
        bucket_sort_spmm1_kernel<<<NB, blk, 0, stream>>>(binned, cursor, edges, rowinfo,
                                                         (const __half2*)xh, (__half2*)z1h,
                                                         cA, N, NB);
    }

    const int sgrid = (N + 15) / 16;              // 16 rows (4 waves) per 256-thread block

    // ---- l = 2: z2 = (c2 A z1 - c3 x)/c0 ----
    {
        int l = 2;
        double c0 = 2.0 * l * (l + a + b) * (2.0 * l + a + b - 2.0);
        double c2 = (2.0 * l + a + b - 1.0) * (2.0 * l + a + b) * (2.0 * l + a + b - 2.0);
        double c3 = 2.0 * (l + a - 1.0) * (l + b - 1.0) * (2.0 * l + a + b);
        spmm_z_kernel<<<sgrid, blk, 0, stream>>>(rowinfo, edges, (const __half2*)z1h,
                                                 (const __half2*)xh, (__half2*)z2h,
                                                 (float)(c2 / c0), (float)(-c3 / c0), N);
    }

    // ---- l = 3 (fused final): z3 = (c2 A z2 - c3 z1)/c0 ; out = 0.25*sum coef_l z_l ----
    {
        int l = 3;
        double c0 = 2.0 * l * (l + a + b) * (2.0 * l + a + b - 2.0);
        double c2 = (2.0 * l + a + b - 1.0) * (2.0 * l + a + b) * (2.0 * l + a + b - 2.0);
        double c3 = 2.0 * (l + a - 1.0) * (l + b - 1.0) * (2.0 * l + a + b);
        spmm_final_kernel<<<sgrid, blk, 0, stream>>>(rowinfo, edges, (const __half2*)z2h,
                                                     (const __half2*)z1h, (const __half2*)xh,
                                                     out, gammas,
                                                     (float)(c2 / c0), (float)(-c3 / c0), N);
    }
}